// Round 1
// baseline (475.939 us; speedup 1.0000x reference)
//
#include <hip/hip_runtime.h>
#include <math.h>

// SpectrumHead: rfft2(512x512) magnitude -> radial/angular histogram -> linear proj.
// B=64, C=3, H=512, W=512, W2=257, K_BINS=16, O_BINS=8, proj=64.
//
// Pass 1: row real-FFTs (2 rows packed per complex FFT), write [512][257] complex.
// Pass 2: column complex FFTs per (b, j), magnitude mean over C, log1p, 24-bin
//         LDS histogram, write per-(b,j) partial histograms (deterministic).
// Pass 3: reduce partials, normalize, h @ W.T + b.
// Chunked over batches so the complex intermediate fits in d_ws.

#define TPB 256
#define PI_F 3.14159265358979323846f

__device__ __forceinline__ void fft512_stages(float2* buf, int t) {
  // In-place radix-2 DIT, input already bit-reverse permuted, 256 threads,
  // one butterfly per thread per stage. Sync between stages only (pairs are
  // disjoint within a stage).
  #pragma unroll
  for (int s = 0; s < 9; s++) {
    int h = 1 << s;
    int jj = t & (h - 1);
    int idx = ((t >> s) << (s + 1)) + jj;
    float ang = -PI_F * (float)jj / (float)h;
    float sn, cs;
    sincosf(ang, &sn, &cs);
    float2 a = buf[idx];
    float2 b = buf[idx + h];
    float2 wb = make_float2(b.x * cs - b.y * sn, b.x * sn + b.y * cs);
    buf[idx]     = make_float2(a.x + wb.x, a.y + wb.y);
    buf[idx + h] = make_float2(a.x - wb.x, a.y - wb.y);
    __syncthreads();
  }
}

__device__ __forceinline__ void get_bins(int i, int j, int& rb, int& ob) {
  // Mirror reference math exactly (fp32):
  // yy = linspace(-1,1,512)[i]; xx = linspace(0,1,257)[j]
  float yy = -1.0f + (float)i * (2.0f / 511.0f);
  float xx = (float)j * (1.0f / 256.0f);
  float rr = sqrtf(yy * yy + xx * xx);
  rr = fminf(rr, 1.0f - 1e-8f);
  float th = atan2f(yy, xx + 1e-9f) + 1.57079632679489662f;
  rb = (int)(rr * 16.0f);
  rb = rb < 0 ? 0 : (rb > 15 ? 15 : rb);
  ob = (int)((th / PI_F) * 8.0f);
  ob = ob < 0 ? 0 : (ob > 7 ? 7 : ob);
}

// Pass 1: blockIdx.x = ic_local*256 + rpair. Two real rows -> one complex FFT.
__global__ __launch_bounds__(TPB) void pass1_kernel(
    const float* __restrict__ x, float2* __restrict__ F, int ic0) {
  __shared__ float2 buf[512];
  int t = threadIdx.x;
  int bid = blockIdx.x;
  int rpair = bid & 255;
  int ic_local = bid >> 8;
  const float* row0 = x + (((size_t)(ic0 + ic_local)) * 512 + (size_t)rpair * 2) * 512;
  const float* row1 = row0 + 512;

  #pragma unroll
  for (int e = 0; e < 2; e++) {
    int i = t + e * 256;
    int dst = __brev((unsigned)i) >> 23;   // 9-bit bit-reversal (involution)
    buf[dst] = make_float2(row0[i], row1[i]);  // coalesced global, scattered LDS
  }
  __syncthreads();
  fft512_stages(buf, t);

  // Unpack packed 2-real-row FFT: Z[k] -> F0[k], F1[k], k = 0..256
  float2* out0 = F + ((size_t)ic_local * 512 + (size_t)rpair * 2) * 257;
  float2* out1 = out0 + 257;
  int k = t;
  int km = (512 - k) & 511;
  float2 zk = buf[k];
  float2 zm = buf[km];
  float2 f0 = make_float2(0.5f * (zk.x + zm.x), 0.5f * (zk.y - zm.y));
  float2 f1 = make_float2(0.5f * (zk.y + zm.y), -0.5f * (zk.x - zm.x));
  out0[k] = f0;
  out1[k] = f1;
  if (t == 0) {
    float2 z = buf[256];   // Nyquist
    out0[256] = make_float2(z.x, 0.0f);
    out1[256] = make_float2(z.y, 0.0f);
  }
}

// Pass 2: blockIdx.x = b_local*257 + j. Column FFT x3 channels, magnitude sum,
// log1p, histogram -> partial[b][j][24].
__global__ __launch_bounds__(TPB) void pass2_kernel(
    const float2* __restrict__ F, float* __restrict__ partial, int b0) {
  __shared__ float2 buf[512];
  __shared__ float hbins[24];
  int t = threadIdx.x;
  int bid = blockIdx.x;
  int j = bid % 257;
  int b_local = bid / 257;

  float magsum0 = 0.0f, magsum1 = 0.0f;
  for (int c = 0; c < 3; c++) {
    const float2* col = F + (size_t)(b_local * 3 + c) * (512 * 257) + j;
    #pragma unroll
    for (int e = 0; e < 2; e++) {
      int i = t + e * 256;
      int dst = __brev((unsigned)i) >> 23;
      buf[dst] = col[(size_t)i * 257];   // strided global read
    }
    __syncthreads();
    fft512_stages(buf, t);
    float2 z0 = buf[t];
    float2 z1 = buf[t + 256];
    magsum0 += sqrtf(z0.x * z0.x + z0.y * z0.y);
    magsum1 += sqrtf(z1.x * z1.x + z1.y * z1.y);
    __syncthreads();   // buf reused next channel
  }

  if (t < 24) hbins[t] = 0.0f;
  __syncthreads();

  // scale: ortho (1/512) * channel mean (1/3) = 1/1536
  float m0 = log1pf(magsum0 * (1.0f / 1536.0f));
  float m1 = log1pf(magsum1 * (1.0f / 1536.0f));
  int rb, ob;
  get_bins(t, j, rb, ob);
  atomicAdd(&hbins[rb], m0);
  atomicAdd(&hbins[16 + ob], m0);
  get_bins(t + 256, j, rb, ob);
  atomicAdd(&hbins[rb], m1);
  atomicAdd(&hbins[16 + ob], m1);
  __syncthreads();

  int b = b0 + b_local;
  if (t < 24) partial[((size_t)b * 257 + j) * 24 + t] = hbins[t];
}

// Pass 3: one block per batch. Reduce 257 partials, normalize, project.
__global__ __launch_bounds__(TPB) void pass3_kernel(
    const float* __restrict__ partial, const float* __restrict__ W,
    const float* __restrict__ bias, float* __restrict__ out) {
  __shared__ float h[24];
  __shared__ float hn[24];
  int b = blockIdx.x;
  int t = threadIdx.x;
  if (t < 24) {
    float s = 0.0f;
    for (int j = 0; j < 257; j++) s += partial[((size_t)b * 257 + j) * 24 + t];
    h[t] = s;
  }
  __syncthreads();
  if (t == 0) {
    float rs = 0.0f, as = 0.0f;
    for (int k = 0; k < 16; k++) rs += h[k];
    for (int k = 16; k < 24; k++) as += h[k];
    for (int k = 0; k < 16; k++) hn[k] = h[k] / (rs + 1e-6f);
    for (int k = 16; k < 24; k++) hn[k] = h[k] / (as + 1e-6f);
  }
  __syncthreads();
  if (t < 64) {
    float acc = bias[t];
    #pragma unroll
    for (int k = 0; k < 24; k++) acc += hn[k] * W[t * 24 + k];
    out[b * 64 + t] = acc;
  }
}

extern "C" void kernel_launch(void* const* d_in, const int* in_sizes, int n_in,
                              void* d_out, int out_size, void* d_ws, size_t ws_size,
                              hipStream_t stream) {
  const float* x    = (const float*)d_in[0];   // [64,3,512,512]
  const float* W    = (const float*)d_in[1];   // [64,24]
  const float* bias = (const float*)d_in[2];   // [64]
  float* out = (float*)d_out;                  // [64,64]

  // ws layout: partial hists [64][257][24] f32, then complex intermediate.
  const size_t partial_bytes = (size_t)64 * 257 * 24 * sizeof(float);  // 1.58 MB
  float* partial = (float*)d_ws;
  float2* F = (float2*)((char*)d_ws + partial_bytes);

  const size_t per_batch = (size_t)3 * 512 * 257 * sizeof(float2);  // 3.16 MB
  size_t avail = ws_size > partial_bytes ? ws_size - partial_bytes : 0;
  int bpc = (int)(avail / per_batch);
  if (bpc < 1) bpc = 1;
  if (bpc > 64) bpc = 64;

  for (int b0 = 0; b0 < 64; b0 += bpc) {
    int nb = (64 - b0) < bpc ? (64 - b0) : bpc;
    pass1_kernel<<<nb * 3 * 256, TPB, 0, stream>>>(x, F, b0 * 3);
    pass2_kernel<<<nb * 257, TPB, 0, stream>>>(F, partial, b0);
  }
  pass3_kernel<<<64, TPB, 0, stream>>>(partial, W, bias, out);
}

// Round 2
// 462.780 us; speedup vs baseline: 1.0284x; 1.0284x over previous
//
#include <hip/hip_runtime.h>
#include <math.h>

// SpectrumHead: rfft2(512x512) magnitude -> radial/angular histogram -> linear proj.
// B=64, C=3, H=512, W=512, W2=257 (padded to 272), K_BINS=16, O_BINS=8, proj=64.
//
// Pass 0: precompute bin-code table in BIT-REVERSED row order: binsrev[p][j] =
//         bins(brev9(p), j) packed rb | ob<<4 (one byte).
// Pass 1: row real-FFTs, 2 rows packed per complex 512-pt DIT FFT (LDS twiddle
//         table, XOR-swizzled LDS to kill the bit-reversal scatter conflict),
//         write [512][272] complex intermediate (padded stride, 128B-aligned rows).
// Pass 2: per (batch, 16-column tile): 3x column FFTs via DIF (natural in,
//         bit-reversed out -> NO permutation), channel-mean magnitude, log1p,
//         24-bin LDS histogram via the binsrev table.
// Pass 3: reduce 17 tile-partials per batch, normalize, h @ W.T + b.

#define TPB 256
#define PI_F 3.14159265358979323846f
#define TWO_PI_F 6.28318530717958647692f
#define W2 257
#define W2P 272            // padded row stride in float2 (multiple of 16 -> 128B rows)
#define NTILE 17           // ceil(257/16)
#define SW(p) ((p) ^ (((p) >> 5) & 15))   // LDS anti-conflict swizzle (involution)

__device__ __forceinline__ int brev9(int p) { return (int)(__brev((unsigned)p) >> 23); }

__device__ __forceinline__ void get_bins(int i, int j, int& rb, int& ob) {
  // Mirror reference math exactly (fp32):
  // yy = linspace(-1,1,512)[i]; xx = linspace(0,1,257)[j]
  float yy = -1.0f + (float)i * (2.0f / 511.0f);
  float xx = (float)j * (1.0f / 256.0f);
  float rr = sqrtf(yy * yy + xx * xx);
  rr = fminf(rr, 1.0f - 1e-8f);
  float th = atan2f(yy, xx + 1e-9f) + 1.57079632679489662f;
  rb = (int)(rr * 16.0f);
  rb = rb < 0 ? 0 : (rb > 15 ? 15 : rb);
  ob = (int)((th / PI_F) * 8.0f);
  ob = ob < 0 ? 0 : (ob > 7 ? 7 : ob);
}

// Pass 0: bin table in bit-reversed row order. blockIdx.x = p (0..511).
__global__ __launch_bounds__(TPB) void pass0_kernel(unsigned char* __restrict__ binsrev) {
  int p = blockIdx.x;
  int i = brev9(p);
  #pragma unroll
  for (int e = 0; e < 2; e++) {
    int j = threadIdx.x + e * 256;
    if (j < W2) {
      int rb, ob;
      get_bins(i, j, rb, ob);
      binsrev[p * W2P + j] = (unsigned char)(rb | (ob << 4));
    }
  }
}

// Pass 1: blockIdx.x = ic_local*256 + rpair. Two real rows -> one complex DIT FFT.
__global__ __launch_bounds__(TPB) void pass1_kernel(
    const float* __restrict__ x, float2* __restrict__ F, int ic0) {
  __shared__ float2 buf[512];
  __shared__ float2 tw[256];
  int t = threadIdx.x;
  int bid = blockIdx.x;
  int rpair = bid & 255;
  int ic_local = bid >> 8;
  const float* row0 = x + (((size_t)(ic0 + ic_local)) * 512 + (size_t)rpair * 2) * 512;
  const float* row1 = row0 + 512;

  {
    float sn, cs;
    sincosf(-TWO_PI_F * (float)t * (1.0f / 512.0f), &sn, &cs);
    tw[t] = make_float2(cs, sn);
  }

  #pragma unroll
  for (int e = 0; e < 2; e++) {
    int i = t + e * 256;
    int dst = brev9(i);
    buf[SW(dst)] = make_float2(row0[i], row1[i]);  // swizzled scatter: <=4-way
  }
  __syncthreads();

  #pragma unroll
  for (int s = 0; s < 9; s++) {
    int h = 1 << s;
    int jj = t & (h - 1);
    int idx = ((t >> s) << (s + 1)) + jj;
    float2 w = tw[jj << (8 - s)];          // exp(-i*pi*jj/h)
    float2 a = buf[SW(idx)];
    float2 b = buf[SW(idx + h)];
    float2 wb = make_float2(b.x * w.x - b.y * w.y, b.x * w.y + b.y * w.x);
    buf[SW(idx)]     = make_float2(a.x + wb.x, a.y + wb.y);
    buf[SW(idx + h)] = make_float2(a.x - wb.x, a.y - wb.y);
    __syncthreads();
  }

  // Unpack packed 2-real-row FFT: Z[k] -> F0[k], F1[k], k = 0..256
  float2* out0 = F + ((size_t)ic_local * 512 + (size_t)rpair * 2) * W2P;
  float2* out1 = out0 + W2P;
  int k = t;
  int km = (512 - k) & 511;
  float2 zk = buf[SW(k)];
  float2 zm = buf[SW(km)];
  float2 f0 = make_float2(0.5f * (zk.x + zm.x), 0.5f * (zk.y - zm.y));
  float2 f1 = make_float2(0.5f * (zk.y + zm.y), -0.5f * (zk.x - zm.x));
  out0[k] = f0;
  out1[k] = f1;
  if (t == 0) {
    float2 z = buf[SW(256)];   // Nyquist
    out0[256] = make_float2(z.x, 0.0f);
    out1[256] = make_float2(z.y, 0.0f);
  }
}

// Pass 2: blockIdx.x = b_local*NTILE + tile. 16 columns per block, DIF FFT.
__global__ __launch_bounds__(TPB) void pass2_kernel(
    const float2* __restrict__ F, const unsigned char* __restrict__ binsrev,
    float* __restrict__ partial, int b0) {
  __shared__ float2 buf[512 * 16];   // 64 KB, layout [row][col]
  __shared__ float2 tw[256];
  __shared__ float hist[24];
  int t = threadIdx.x;
  int tile = blockIdx.x % NTILE;
  int b_local = blockIdx.x / NTILE;
  int col = t & 15;
  int rowg = t >> 4;                 // 0..15
  int j = tile * 16 + col;
  bool jvalid = (j < W2);

  {
    float sn, cs;
    sincosf(-TWO_PI_F * (float)t * (1.0f / 512.0f), &sn, &cs);
    tw[t] = make_float2(cs, sn);
  }
  if (t < 24) hist[t] = 0.0f;

  float mag[32];
  #pragma unroll
  for (int q = 0; q < 32; ++q) mag[q] = 0.0f;

  for (int c = 0; c < 3; ++c) {
    const float2* colp = F + (size_t)(b_local * 3 + c) * (512 * W2P);
    __syncthreads();   // buf free (covers tw/hist init on first iter)
    #pragma unroll 8
    for (int q = 0; q < 32; ++q) {
      int r = rowg + (q << 4);
      float2 v = jvalid ? colp[(size_t)r * W2P + j] : make_float2(0.0f, 0.0f);
      buf[r * 16 + col] = v;         // coalesced 128B row segments
    }
    __syncthreads();
    // DIF: natural order in, bit-reversed order out (no permutation needed).
    for (int s = 8; s >= 0; --s) {
      int h = 1 << s;
      #pragma unroll 4
      for (int q = 0; q < 16; ++q) {
        int bf = rowg + (q << 4);
        int jj = bf & (h - 1);
        int idx = ((bf >> s) << (s + 1)) + jj;
        float2 w = tw[jj << (8 - s)];   // exp(-i*pi*jj/h)
        float2 a = buf[idx * 16 + col];
        float2 b = buf[(idx + h) * 16 + col];
        float dx = a.x - b.x, dy = a.y - b.y;
        buf[idx * 16 + col]       = make_float2(a.x + b.x, a.y + b.y);
        buf[(idx + h) * 16 + col] = make_float2(dx * w.x - dy * w.y, dx * w.y + dy * w.x);
      }
      __syncthreads();
    }
    #pragma unroll
    for (int q = 0; q < 32; ++q) {     // full unroll: mag[] must stay in regs
      int p = rowg + (q << 4);
      float2 z = buf[p * 16 + col];
      mag[q] += sqrtf(z.x * z.x + z.y * z.y);
    }
  }

  if (jvalid) {
    #pragma unroll
    for (int q = 0; q < 32; ++q) {     // full unroll: mag[] must stay in regs
      int p = rowg + (q << 4);
      int code = binsrev[p * W2P + j];
      // scale: ortho (1/512) * channel mean (1/3) = 1/1536
      float m = log1pf(mag[q] * (1.0f / 1536.0f));
      atomicAdd(&hist[code & 15], m);
      atomicAdd(&hist[16 + (code >> 4)], m);
    }
  }
  __syncthreads();
  int b = b0 + b_local;
  if (t < 24) partial[((size_t)b * NTILE + tile) * 24 + t] = hist[t];
}

// Pass 3: one block per batch. Reduce NTILE partials, normalize, project.
__global__ __launch_bounds__(TPB) void pass3_kernel(
    const float* __restrict__ partial, const float* __restrict__ W,
    const float* __restrict__ bias, float* __restrict__ out) {
  __shared__ float h[24];
  __shared__ float hn[24];
  int b = blockIdx.x;
  int t = threadIdx.x;
  if (t < 24) {
    float s = 0.0f;
    for (int tile = 0; tile < NTILE; tile++)
      s += partial[((size_t)b * NTILE + tile) * 24 + t];
    h[t] = s;
  }
  __syncthreads();
  if (t == 0) {
    float rs = 0.0f, as = 0.0f;
    for (int k = 0; k < 16; k++) rs += h[k];
    for (int k = 16; k < 24; k++) as += h[k];
    for (int k = 0; k < 16; k++) hn[k] = h[k] / (rs + 1e-6f);
    for (int k = 16; k < 24; k++) hn[k] = h[k] / (as + 1e-6f);
  }
  __syncthreads();
  if (t < 64) {
    float acc = bias[t];
    #pragma unroll
    for (int k = 0; k < 24; k++) acc += hn[k] * W[t * 24 + k];
    out[b * 64 + t] = acc;
  }
}

extern "C" void kernel_launch(void* const* d_in, const int* in_sizes, int n_in,
                              void* d_out, int out_size, void* d_ws, size_t ws_size,
                              hipStream_t stream) {
  const float* x    = (const float*)d_in[0];   // [64,3,512,512]
  const float* W    = (const float*)d_in[1];   // [64,24]
  const float* bias = (const float*)d_in[2];   // [64]
  float* out = (float*)d_out;                  // [64,64]

  // ws layout: partial hists | binsrev table | complex intermediate F
  const size_t partial_bytes = (size_t)64 * NTILE * 24 * sizeof(float);
  size_t off_bins = (partial_bytes + 255) & ~(size_t)255;
  const size_t bins_bytes = (size_t)512 * W2P;
  size_t off_F = ((off_bins + bins_bytes) + 255) & ~(size_t)255;

  float* partial = (float*)d_ws;
  unsigned char* binsrev = (unsigned char*)d_ws + off_bins;
  float2* F = (float2*)((char*)d_ws + off_F);

  const size_t per_batch = (size_t)3 * 512 * W2P * sizeof(float2);  // 3.34 MB
  size_t avail = ws_size > off_F ? ws_size - off_F : 0;
  int bpc = (int)(avail / per_batch);
  if (bpc < 1) bpc = 1;
  if (bpc > 64) bpc = 64;

  pass0_kernel<<<512, TPB, 0, stream>>>(binsrev);

  for (int b0 = 0; b0 < 64; b0 += bpc) {
    int nb = (64 - b0) < bpc ? (64 - b0) : bpc;
    pass1_kernel<<<nb * 3 * 256, TPB, 0, stream>>>(x, F, b0 * 3);
    pass2_kernel<<<nb * NTILE, TPB, 0, stream>>>(F, binsrev, partial, b0);
  }
  pass3_kernel<<<64, TPB, 0, stream>>>(partial, W, bias, out);
}

// Round 3
// 420.138 us; speedup vs baseline: 1.1328x; 1.1015x over previous
//
#include <hip/hip_runtime.h>
#include <math.h>

// SpectrumHead: rfft2(512x512) magnitude -> radial/angular histogram -> linear proj.
// B=64, C=3, H=512, W=512, W2=257 (padded to 272), K_BINS=16, O_BINS=8, proj=64.
//
// Pass 0: bin-code table binsNat[row][j] = rb | ob<<4 (natural row order).
// Pass 1: row real-FFTs, 2 rows packed per complex 512-pt DIT FFT (LDS twiddles,
//         XOR-swizzled LDS), write [512][272] complex intermediate.
// Pass 2: column FFTs via four-step 512=32x16 REGISTER FFT: per thread (col,n1)
//         32-pt FFT fully in VGPRs (compile-time twiddles), W_512^(n1*k2) twiddle,
//         one 32KB LDS transpose per k2-half, 16-pt register FFT, magnitudes,
//         log1p + 24-bin LDS histogram. 4 blocks/CU, ~13 barriers/block.
// Pass 3: reduce tile-partials per batch, normalize, h @ W.T + b.

#define TPB 256
#define PI_F 3.14159265358979323846f
#define TWO_PI_F 6.28318530717958647692f
#define W2 257
#define W2P 272            // padded row stride in float2
#define NTILE 17           // ceil(257/16)
#define SW(p) ((p) ^ (((p) >> 5) & 15))   // pass1 LDS anti-conflict swizzle

__device__ __forceinline__ int brev9(int p) { return (int)(__brev((unsigned)p) >> 23); }

// exp(-2*pi*i*k/32), k = 0..15
static constexpr float TW32_RE[16] = {
   1.0f,          0.98078528f,  0.92387953f,  0.83146961f,
   0.70710678f,   0.55557023f,  0.38268343f,  0.19509032f,
   0.0f,         -0.19509032f, -0.38268343f, -0.55557023f,
  -0.70710678f,  -0.83146961f, -0.92387953f, -0.98078528f };
static constexpr float TW32_IM[16] = {
  -0.0f,         -0.19509032f, -0.38268343f, -0.55557023f,
  -0.70710678f,  -0.83146961f, -0.92387953f, -0.98078528f,
  -1.0f,         -0.98078528f, -0.92387953f, -0.83146961f,
  -0.70710678f,  -0.55557023f, -0.38268343f, -0.19509032f };

static constexpr int BR5[32] = {0,16,8,24,4,20,12,28,2,18,10,26,6,22,14,30,
                                1,17,9,25,5,21,13,29,3,19,11,27,7,23,15,31};
static constexpr int BR4[16] = {0,8,4,12,2,10,6,14,1,9,5,13,3,11,7,15};

// In-register DIT FFT, N = 2^LOGN (LOGN <= 5). Input must be bit-rev permuted;
// output natural order. All indices compile-time (full unroll) -> stays in VGPRs.
template <int LOGN>
__device__ __forceinline__ void fft_reg(float2* z) {
  const int N = 1 << LOGN;
  #pragma unroll
  for (int s = 0; s < LOGN; ++s) {
    const int h = 1 << s;
    #pragma unroll
    for (int g0 = 0; g0 < N; g0 += 2 * h) {
      #pragma unroll
      for (int jj = 0; jj < h; ++jj) {
        const int k = jj << (4 - s);          // index into TW32 (exp(-i*pi*jj/h))
        const float wr = TW32_RE[k], wi = TW32_IM[k];
        float2 a = z[g0 + jj];
        float2 b = z[g0 + jj + h];
        float tr = b.x * wr - b.y * wi;
        float ti = b.x * wi + b.y * wr;
        z[g0 + jj]     = make_float2(a.x + tr, a.y + ti);
        z[g0 + jj + h] = make_float2(a.x - tr, a.y - ti);
      }
    }
  }
}

__device__ __forceinline__ void get_bins(int i, int j, int& rb, int& ob) {
  float yy = -1.0f + (float)i * (2.0f / 511.0f);
  float xx = (float)j * (1.0f / 256.0f);
  float rr = sqrtf(yy * yy + xx * xx);
  rr = fminf(rr, 1.0f - 1e-8f);
  float th = atan2f(yy, xx + 1e-9f) + 1.57079632679489662f;
  rb = (int)(rr * 16.0f);
  rb = rb < 0 ? 0 : (rb > 15 ? 15 : rb);
  ob = (int)((th / PI_F) * 8.0f);
  ob = ob < 0 ? 0 : (ob > 7 ? 7 : ob);
}

// Pass 0: bin table, natural row order. blockIdx.x = row i.
__global__ __launch_bounds__(TPB) void pass0_kernel(unsigned char* __restrict__ binsNat) {
  int i = blockIdx.x;
  #pragma unroll
  for (int e = 0; e < 2; e++) {
    int j = threadIdx.x + e * 256;
    if (j < W2) {
      int rb, ob;
      get_bins(i, j, rb, ob);
      binsNat[i * W2P + j] = (unsigned char)(rb | (ob << 4));
    }
  }
}

// Pass 1: blockIdx.x = ic_local*256 + rpair. Two real rows -> one complex DIT FFT.
__global__ __launch_bounds__(TPB) void pass1_kernel(
    const float* __restrict__ x, float2* __restrict__ F, int ic0) {
  __shared__ float2 buf[512];
  __shared__ float2 tw[256];
  int t = threadIdx.x;
  int bid = blockIdx.x;
  int rpair = bid & 255;
  int ic_local = bid >> 8;
  const float* row0 = x + (((size_t)(ic0 + ic_local)) * 512 + (size_t)rpair * 2) * 512;
  const float* row1 = row0 + 512;

  {
    float sn, cs;
    sincosf(-TWO_PI_F * (float)t * (1.0f / 512.0f), &sn, &cs);
    tw[t] = make_float2(cs, sn);
  }

  #pragma unroll
  for (int e = 0; e < 2; e++) {
    int i = t + e * 256;
    int dst = brev9(i);
    buf[SW(dst)] = make_float2(row0[i], row1[i]);
  }
  __syncthreads();

  #pragma unroll
  for (int s = 0; s < 9; s++) {
    int h = 1 << s;
    int jj = t & (h - 1);
    int idx = ((t >> s) << (s + 1)) + jj;
    float2 w = tw[jj << (8 - s)];
    float2 a = buf[SW(idx)];
    float2 b = buf[SW(idx + h)];
    float2 wb = make_float2(b.x * w.x - b.y * w.y, b.x * w.y + b.y * w.x);
    buf[SW(idx)]     = make_float2(a.x + wb.x, a.y + wb.y);
    buf[SW(idx + h)] = make_float2(a.x - wb.x, a.y - wb.y);
    __syncthreads();
  }

  float2* out0 = F + ((size_t)ic_local * 512 + (size_t)rpair * 2) * W2P;
  float2* out1 = out0 + W2P;
  int k = t;
  int km = (512 - k) & 511;
  float2 zk = buf[SW(k)];
  float2 zm = buf[SW(km)];
  out0[k] = make_float2(0.5f * (zk.x + zm.x), 0.5f * (zk.y - zm.y));
  out1[k] = make_float2(0.5f * (zk.y + zm.y), -0.5f * (zk.x - zm.x));
  if (t == 0) {
    float2 z = buf[SW(256)];
    out0[256] = make_float2(z.x, 0.0f);
    out1[256] = make_float2(z.y, 0.0f);
  }
}

// Pass 2: blockIdx.x = b_local*NTILE + tile. 16 columns/block, four-step reg FFT.
__global__ __launch_bounds__(TPB, 4) void pass2_kernel(
    const float2* __restrict__ F, const unsigned char* __restrict__ binsNat,
    float* __restrict__ partial, int b0) {
  __shared__ float2 trbuf[16 * 16 * 16];   // [n1][k2l][col], 32 KB
  __shared__ float2 tw512[512];            // exp(-2pi i k/512), 4 KB
  __shared__ float hist[24];
  int t = threadIdx.x;
  int tile = blockIdx.x % NTILE;
  int b_local = blockIdx.x / NTILE;
  int col = t & 15;
  int g = t >> 4;                 // n1 (write role) / k2l (read role), 0..15
  int j = tile * 16 + col;
  bool jvalid = (j < W2);

  {
    float sn, cs;
    sincosf(-TWO_PI_F * (float)t * (1.0f / 512.0f), &sn, &cs);
    tw512[t] = make_float2(cs, sn);
    sincosf(-TWO_PI_F * (float)(t + 256) * (1.0f / 512.0f), &sn, &cs);
    tw512[t + 256] = make_float2(cs, sn);
  }
  if (t < 24) hist[t] = 0.0f;
  __syncthreads();

  const float2* Fb = F + (size_t)(b_local * 3) * (512 * W2P);

  // k2 halves: recompute the 32-pt reg FFT per half so the transpose fits 32 KB.
  #pragma unroll
  for (int chunk = 0; chunk < 2; ++chunk) {
    const int k2base = chunk * 16;
    float mag16[16];
    #pragma unroll
    for (int k1 = 0; k1 < 16; ++k1) mag16[k1] = 0.0f;

    for (int c = 0; c < 3; ++c) {
      // load 32 elems: rows g + 16*n2, column j (bitrev into z, all reg-resident)
      const float2* colp = Fb + (size_t)c * (512 * W2P) + (size_t)g * W2P + j;
      float2 z[32];
      #pragma unroll
      for (int n2 = 0; n2 < 32; ++n2) {
        float2 v = make_float2(0.0f, 0.0f);
        if (jvalid) v = colp[(size_t)n2 * (16 * W2P)];
        z[BR5[n2]] = v;
      }
      fft_reg<5>(z);                         // A[n1][k2], k2 natural in z[]
      // twiddle W_512^(n1*k2) and write this k2-half to LDS transpose buffer
      #pragma unroll
      for (int q = 0; q < 16; ++q) {
        const int k2 = k2base + q;
        float2 w = tw512[g * k2];
        float2 v = z[k2];
        trbuf[(g << 8) + (q << 4) + col] =
            make_float2(v.x * w.x - v.y * w.y, v.x * w.y + v.y * w.x);
      }
      __syncthreads();
      // read transposed: this thread owns (k2 = k2base+g, col); gather n1=0..15
      float2 r[16];
      #pragma unroll
      for (int i = 0; i < 16; ++i)
        r[BR4[i]] = trbuf[(i << 8) + (g << 4) + col];
      fft_reg<4>(r);                         // r[k1] = X[k2 + 32*k1]
      #pragma unroll
      for (int k1 = 0; k1 < 16; ++k1)
        mag16[k1] += sqrtf(r[k1].x * r[k1].x + r[k1].y * r[k1].y);
      __syncthreads();                       // trbuf free for next channel
    }

    if (jvalid) {
      const int k2 = k2base + g;
      #pragma unroll
      for (int k1 = 0; k1 < 16; ++k1) {
        int row = k2 + (k1 << 5);
        int code = binsNat[row * W2P + j];
        // scale: ortho (1/512) * channel mean (1/3) = 1/1536
        float m = log1pf(mag16[k1] * (1.0f / 1536.0f));
        atomicAdd(&hist[code & 15], m);
        atomicAdd(&hist[16 + (code >> 4)], m);
      }
    }
  }
  __syncthreads();
  int b = b0 + b_local;
  if (t < 24) partial[((size_t)b * NTILE + tile) * 24 + t] = hist[t];
}

// Pass 3: one block per batch. Reduce NTILE partials, normalize, project.
__global__ __launch_bounds__(TPB) void pass3_kernel(
    const float* __restrict__ partial, const float* __restrict__ W,
    const float* __restrict__ bias, float* __restrict__ out) {
  __shared__ float h[24];
  __shared__ float hn[24];
  int b = blockIdx.x;
  int t = threadIdx.x;
  if (t < 24) {
    float s = 0.0f;
    for (int tile = 0; tile < NTILE; tile++)
      s += partial[((size_t)b * NTILE + tile) * 24 + t];
    h[t] = s;
  }
  __syncthreads();
  if (t == 0) {
    float rs = 0.0f, as = 0.0f;
    for (int k = 0; k < 16; k++) rs += h[k];
    for (int k = 16; k < 24; k++) as += h[k];
    for (int k = 0; k < 16; k++) hn[k] = h[k] / (rs + 1e-6f);
    for (int k = 16; k < 24; k++) hn[k] = h[k] / (as + 1e-6f);
  }
  __syncthreads();
  if (t < 64) {
    float acc = bias[t];
    #pragma unroll
    for (int k = 0; k < 24; k++) acc += hn[k] * W[t * 24 + k];
    out[b * 64 + t] = acc;
  }
}

extern "C" void kernel_launch(void* const* d_in, const int* in_sizes, int n_in,
                              void* d_out, int out_size, void* d_ws, size_t ws_size,
                              hipStream_t stream) {
  const float* x    = (const float*)d_in[0];   // [64,3,512,512]
  const float* W    = (const float*)d_in[1];   // [64,24]
  const float* bias = (const float*)d_in[2];   // [64]
  float* out = (float*)d_out;                  // [64,64]

  // ws layout: partial hists | bin table | complex intermediate F
  const size_t partial_bytes = (size_t)64 * NTILE * 24 * sizeof(float);
  size_t off_bins = (partial_bytes + 255) & ~(size_t)255;
  const size_t bins_bytes = (size_t)512 * W2P;
  size_t off_F = ((off_bins + bins_bytes) + 255) & ~(size_t)255;

  float* partial = (float*)d_ws;
  unsigned char* binsNat = (unsigned char*)d_ws + off_bins;
  float2* F = (float2*)((char*)d_ws + off_F);

  const size_t per_batch = (size_t)3 * 512 * W2P * sizeof(float2);  // 3.34 MB
  size_t avail = ws_size > off_F ? ws_size - off_F : 0;
  int bpc = (int)(avail / per_batch);
  if (bpc < 1) bpc = 1;
  if (bpc > 64) bpc = 64;

  pass0_kernel<<<512, TPB, 0, stream>>>(binsNat);

  for (int b0 = 0; b0 < 64; b0 += bpc) {
    int nb = (64 - b0) < bpc ? (64 - b0) : bpc;
    pass1_kernel<<<nb * 3 * 256, TPB, 0, stream>>>(x, F, b0 * 3);
    pass2_kernel<<<nb * NTILE, TPB, 0, stream>>>(F, binsNat, partial, b0);
  }
  pass3_kernel<<<64, TPB, 0, stream>>>(partial, W, bias, out);
}

// Round 4
// 291.828 us; speedup vs baseline: 1.6309x; 1.4397x over previous
//
#include <hip/hip_runtime.h>
#include <math.h>

// SpectrumHead: rfft2(512x512) magnitude -> radial/angular histogram -> linear proj.
// B=64, C=3, H=512, W=512, W2=257 (padded to 272), K_BINS=16, O_BINS=8, proj=64.
//
// Pass 0: bin-code table binsNat[row][j] = rb | ob<<4 (natural row order).
// Pass 1: row real-FFTs, 2 rows packed per complex 512-pt DIT FFT (LDS twiddles,
//         XOR-swizzled LDS), write [512][272] complex intermediate.
// Pass 2: column FFTs via four-step 512=32x16 REGISTER FFT: per thread (col,n1)
//         ONE 32-pt FFT in VGPRs per channel (compile-time twiddles); its output
//         feeds BOTH k2-half transposes non-destructively (no recompute, F read
//         once). 32KB LDS transpose buffer, 16-pt register FFT, magnitudes,
//         log1p + 24-bin LDS histogram. launch_bounds(256,3): no spills.
// Pass 3: reduce tile-partials per batch, normalize, h @ W.T + b.

#define TPB 256
#define PI_F 3.14159265358979323846f
#define TWO_PI_F 6.28318530717958647692f
#define W2 257
#define W2P 272            // padded row stride in float2
#define NTILE 17           // ceil(257/16)
#define SW(p) ((p) ^ (((p) >> 5) & 15))   // pass1 LDS anti-conflict swizzle

__device__ __forceinline__ int brev9(int p) { return (int)(__brev((unsigned)p) >> 23); }

// exp(-2*pi*i*k/32), k = 0..15
static constexpr float TW32_RE[16] = {
   1.0f,          0.98078528f,  0.92387953f,  0.83146961f,
   0.70710678f,   0.55557023f,  0.38268343f,  0.19509032f,
   0.0f,         -0.19509032f, -0.38268343f, -0.55557023f,
  -0.70710678f,  -0.83146961f, -0.92387953f, -0.98078528f };
static constexpr float TW32_IM[16] = {
  -0.0f,         -0.19509032f, -0.38268343f, -0.55557023f,
  -0.70710678f,  -0.83146961f, -0.92387953f, -0.98078528f,
  -1.0f,         -0.98078528f, -0.92387953f, -0.83146961f,
  -0.70710678f,  -0.55557023f, -0.38268343f, -0.19509032f };

static constexpr int BR5[32] = {0,16,8,24,4,20,12,28,2,18,10,26,6,22,14,30,
                                1,17,9,25,5,21,13,29,3,19,11,27,7,23,15,31};
static constexpr int BR4[16] = {0,8,4,12,2,10,6,14,1,9,5,13,3,11,7,15};

// In-register DIT FFT, N = 2^LOGN (LOGN <= 5). Input must be bit-rev permuted;
// output natural order. All indices compile-time (full unroll) -> stays in VGPRs.
template <int LOGN>
__device__ __forceinline__ void fft_reg(float2* z) {
  const int N = 1 << LOGN;
  #pragma unroll
  for (int s = 0; s < LOGN; ++s) {
    const int h = 1 << s;
    #pragma unroll
    for (int g0 = 0; g0 < N; g0 += 2 * h) {
      #pragma unroll
      for (int jj = 0; jj < h; ++jj) {
        const int k = jj << (4 - s);          // index into TW32 (exp(-i*pi*jj/h))
        const float wr = TW32_RE[k], wi = TW32_IM[k];
        float2 a = z[g0 + jj];
        float2 b = z[g0 + jj + h];
        float tr = b.x * wr - b.y * wi;
        float ti = b.x * wi + b.y * wr;
        z[g0 + jj]     = make_float2(a.x + tr, a.y + ti);
        z[g0 + jj + h] = make_float2(a.x - tr, a.y - ti);
      }
    }
  }
}

__device__ __forceinline__ void get_bins(int i, int j, int& rb, int& ob) {
  float yy = -1.0f + (float)i * (2.0f / 511.0f);
  float xx = (float)j * (1.0f / 256.0f);
  float rr = sqrtf(yy * yy + xx * xx);
  rr = fminf(rr, 1.0f - 1e-8f);
  float th = atan2f(yy, xx + 1e-9f) + 1.57079632679489662f;
  rb = (int)(rr * 16.0f);
  rb = rb < 0 ? 0 : (rb > 15 ? 15 : rb);
  ob = (int)((th / PI_F) * 8.0f);
  ob = ob < 0 ? 0 : (ob > 7 ? 7 : ob);
}

// Pass 0: bin table, natural row order. blockIdx.x = row i.
__global__ __launch_bounds__(TPB) void pass0_kernel(unsigned char* __restrict__ binsNat) {
  int i = blockIdx.x;
  #pragma unroll
  for (int e = 0; e < 2; e++) {
    int j = threadIdx.x + e * 256;
    if (j < W2) {
      int rb, ob;
      get_bins(i, j, rb, ob);
      binsNat[i * W2P + j] = (unsigned char)(rb | (ob << 4));
    }
  }
}

// Pass 1: blockIdx.x = ic_local*256 + rpair. Two real rows -> one complex DIT FFT.
__global__ __launch_bounds__(TPB) void pass1_kernel(
    const float* __restrict__ x, float2* __restrict__ F, int ic0) {
  __shared__ float2 buf[512];
  __shared__ float2 tw[256];
  int t = threadIdx.x;
  int bid = blockIdx.x;
  int rpair = bid & 255;
  int ic_local = bid >> 8;
  const float* row0 = x + (((size_t)(ic0 + ic_local)) * 512 + (size_t)rpair * 2) * 512;
  const float* row1 = row0 + 512;

  {
    float sn, cs;
    sincosf(-TWO_PI_F * (float)t * (1.0f / 512.0f), &sn, &cs);
    tw[t] = make_float2(cs, sn);
  }

  #pragma unroll
  for (int e = 0; e < 2; e++) {
    int i = t + e * 256;
    int dst = brev9(i);
    buf[SW(dst)] = make_float2(row0[i], row1[i]);
  }
  __syncthreads();

  #pragma unroll
  for (int s = 0; s < 9; s++) {
    int h = 1 << s;
    int jj = t & (h - 1);
    int idx = ((t >> s) << (s + 1)) + jj;
    float2 w = tw[jj << (8 - s)];
    float2 a = buf[SW(idx)];
    float2 b = buf[SW(idx + h)];
    float2 wb = make_float2(b.x * w.x - b.y * w.y, b.x * w.y + b.y * w.x);
    buf[SW(idx)]     = make_float2(a.x + wb.x, a.y + wb.y);
    buf[SW(idx + h)] = make_float2(a.x - wb.x, a.y - wb.y);
    __syncthreads();
  }

  float2* out0 = F + ((size_t)ic_local * 512 + (size_t)rpair * 2) * W2P;
  float2* out1 = out0 + W2P;
  int k = t;
  int km = (512 - k) & 511;
  float2 zk = buf[SW(k)];
  float2 zm = buf[SW(km)];
  out0[k] = make_float2(0.5f * (zk.x + zm.x), 0.5f * (zk.y - zm.y));
  out1[k] = make_float2(0.5f * (zk.y + zm.y), -0.5f * (zk.x - zm.x));
  if (t == 0) {
    float2 z = buf[SW(256)];
    out0[256] = make_float2(z.x, 0.0f);
    out1[256] = make_float2(z.y, 0.0f);
  }
}

// Pass 2: blockIdx.x = b_local*NTILE + tile. 16 columns/block, four-step reg FFT.
__global__ __launch_bounds__(TPB, 3) void pass2_kernel(
    const float2* __restrict__ F, const unsigned char* __restrict__ binsNat,
    float* __restrict__ partial, int b0) {
  __shared__ float2 trbuf[16 * 16 * 16];   // [n1][k2l][col], 32 KB
  __shared__ float2 tw512[512];            // exp(-2pi i k/512), 4 KB
  __shared__ float hist[24];
  int t = threadIdx.x;
  int tile = blockIdx.x % NTILE;
  int b_local = blockIdx.x / NTILE;
  int col = t & 15;
  int g = t >> 4;                 // n1 (write role) / k2-within-chunk (read role)
  int j = tile * 16 + col;
  bool jvalid = (j < W2);

  {
    float sn, cs;
    sincosf(-TWO_PI_F * (float)t * (1.0f / 512.0f), &sn, &cs);
    tw512[t] = make_float2(cs, sn);
    sincosf(-TWO_PI_F * (float)(t + 256) * (1.0f / 512.0f), &sn, &cs);
    tw512[t + 256] = make_float2(cs, sn);
  }
  if (t < 24) hist[t] = 0.0f;
  __syncthreads();

  const float2* Fb = F + (size_t)(b_local * 3) * (512 * W2P);

  float magA[16], magB[16];
  #pragma unroll
  for (int k1 = 0; k1 < 16; ++k1) { magA[k1] = 0.0f; magB[k1] = 0.0f; }

  for (int c = 0; c < 3; ++c) {
    // load 32 elems: rows g + 16*n2, column j (bitrev into z, all reg-resident)
    const float2* colp = Fb + (size_t)c * (512 * W2P) + (size_t)g * W2P + j;
    float2 z[32];
    #pragma unroll
    for (int n2 = 0; n2 < 32; ++n2) {
      float2 v = make_float2(0.0f, 0.0f);
      if (jvalid) v = colp[(size_t)n2 * (16 * W2P)];
      z[BR5[n2]] = v;
    }
    fft_reg<5>(z);                         // z[k2] = A[n1=g][k2], k2 natural

    // ---- chunk A: k2 = 0..15 (reads z non-destructively) ----
    #pragma unroll
    for (int q = 0; q < 16; ++q) {
      float2 w = tw512[g * q];             // W_512^(n1*k2)
      float2 v = z[q];
      trbuf[(g << 8) + (q << 4) + col] =
          make_float2(v.x * w.x - v.y * w.y, v.x * w.y + v.y * w.x);
    }
    __syncthreads();
    {
      float2 r[16];
      #pragma unroll
      for (int i = 0; i < 16; ++i)
        r[BR4[i]] = trbuf[(i << 8) + (g << 4) + col];
      fft_reg<4>(r);                       // r[k1] = X[k2 + 32*k1], k2 = g
      #pragma unroll
      for (int k1 = 0; k1 < 16; ++k1)
        magA[k1] += sqrtf(r[k1].x * r[k1].x + r[k1].y * r[k1].y);
    }
    __syncthreads();

    // ---- chunk B: k2 = 16..31 (same z registers) ----
    #pragma unroll
    for (int q = 0; q < 16; ++q) {
      const int k2 = 16 + q;
      float2 w = tw512[g * k2];
      float2 v = z[k2];
      trbuf[(g << 8) + (q << 4) + col] =
          make_float2(v.x * w.x - v.y * w.y, v.x * w.y + v.y * w.x);
    }
    __syncthreads();
    {
      float2 r[16];
      #pragma unroll
      for (int i = 0; i < 16; ++i)
        r[BR4[i]] = trbuf[(i << 8) + (g << 4) + col];
      fft_reg<4>(r);                       // r[k1] = X[k2 + 32*k1], k2 = 16 + g
      #pragma unroll
      for (int k1 = 0; k1 < 16; ++k1)
        magB[k1] += sqrtf(r[k1].x * r[k1].x + r[k1].y * r[k1].y);
    }
    __syncthreads();                       // trbuf free for next channel
  }

  if (jvalid) {
    #pragma unroll
    for (int k1 = 0; k1 < 16; ++k1) {
      // chunk A rows: k2 = g
      int rowA = g + (k1 << 5);
      int codeA = binsNat[rowA * W2P + j];
      // scale: ortho (1/512) * channel mean (1/3) = 1/1536
      float mA = log1pf(magA[k1] * (1.0f / 1536.0f));
      atomicAdd(&hist[codeA & 15], mA);
      atomicAdd(&hist[16 + (codeA >> 4)], mA);
      // chunk B rows: k2 = 16 + g
      int rowB = 16 + g + (k1 << 5);
      int codeB = binsNat[rowB * W2P + j];
      float mB = log1pf(magB[k1] * (1.0f / 1536.0f));
      atomicAdd(&hist[codeB & 15], mB);
      atomicAdd(&hist[16 + (codeB >> 4)], mB);
    }
  }
  __syncthreads();
  int b = b0 + b_local;
  if (t < 24) partial[((size_t)b * NTILE + tile) * 24 + t] = hist[t];
}

// Pass 3: one block per batch. Reduce NTILE partials, normalize, project.
__global__ __launch_bounds__(TPB) void pass3_kernel(
    const float* __restrict__ partial, const float* __restrict__ W,
    const float* __restrict__ bias, float* __restrict__ out) {
  __shared__ float h[24];
  __shared__ float hn[24];
  int b = blockIdx.x;
  int t = threadIdx.x;
  if (t < 24) {
    float s = 0.0f;
    for (int tile = 0; tile < NTILE; tile++)
      s += partial[((size_t)b * NTILE + tile) * 24 + t];
    h[t] = s;
  }
  __syncthreads();
  if (t == 0) {
    float rs = 0.0f, as = 0.0f;
    for (int k = 0; k < 16; k++) rs += h[k];
    for (int k = 16; k < 24; k++) as += h[k];
    for (int k = 0; k < 16; k++) hn[k] = h[k] / (rs + 1e-6f);
    for (int k = 16; k < 24; k++) hn[k] = h[k] / (as + 1e-6f);
  }
  __syncthreads();
  if (t < 64) {
    float acc = bias[t];
    #pragma unroll
    for (int k = 0; k < 24; k++) acc += hn[k] * W[t * 24 + k];
    out[b * 64 + t] = acc;
  }
}

extern "C" void kernel_launch(void* const* d_in, const int* in_sizes, int n_in,
                              void* d_out, int out_size, void* d_ws, size_t ws_size,
                              hipStream_t stream) {
  const float* x    = (const float*)d_in[0];   // [64,3,512,512]
  const float* W    = (const float*)d_in[1];   // [64,24]
  const float* bias = (const float*)d_in[2];   // [64]
  float* out = (float*)d_out;                  // [64,64]

  // ws layout: partial hists | bin table | complex intermediate F
  const size_t partial_bytes = (size_t)64 * NTILE * 24 * sizeof(float);
  size_t off_bins = (partial_bytes + 255) & ~(size_t)255;
  const size_t bins_bytes = (size_t)512 * W2P;
  size_t off_F = ((off_bins + bins_bytes) + 255) & ~(size_t)255;

  float* partial = (float*)d_ws;
  unsigned char* binsNat = (unsigned char*)d_ws + off_bins;
  float2* F = (float2*)((char*)d_ws + off_F);

  const size_t per_batch = (size_t)3 * 512 * W2P * sizeof(float2);  // 3.34 MB
  size_t avail = ws_size > off_F ? ws_size - off_F : 0;
  int bpc = (int)(avail / per_batch);
  if (bpc < 1) bpc = 1;
  if (bpc > 64) bpc = 64;

  pass0_kernel<<<512, TPB, 0, stream>>>(binsNat);

  for (int b0 = 0; b0 < 64; b0 += bpc) {
    int nb = (64 - b0) < bpc ? (64 - b0) : bpc;
    pass1_kernel<<<nb * 3 * 256, TPB, 0, stream>>>(x, F, b0 * 3);
    pass2_kernel<<<nb * NTILE, TPB, 0, stream>>>(F, binsNat, partial, b0);
  }
  pass3_kernel<<<64, TPB, 0, stream>>>(partial, W, bias, out);
}